// Round 7
// baseline (278.112 us; speedup 1.0000x reference)
//
#include <hip/hip_runtime.h>
#include <cstdint>

#define BN_EPS 1e-5f

static constexpr int NB = 8192;
static constexpr int JLIN = 500;

// ---------------------------------------------------------------------------
// ws layout
//  h2b   [8192][128] u32   @ 0         4 MB   (row-major per sample)
//  (unused)               @ 4194304
//  wlin4 [8][32][64][4] u32 @ 4718592  256 KB (per-jw LDS image: kq, j, q)
//  cdat  [640]       u32   @ 4980736   (masks plane-major [tap][c] + T[c] @576)
//  lut   [512]       u32   @ 4983296
//  wout  [10*16]     u32   @ 4985344   (read as u64[8] per o)
//  Tlin  [512]       i32   @ 4985984
//  Bs    [8192]      i32   @ 4988032   32 KB
// ---------------------------------------------------------------------------

// ---------------------------------------------------------------------------
// pack kernel, grid = 508 blocks (unchanged except cdat plane layout)
// ---------------------------------------------------------------------------
__global__ __launch_bounds__(256) void pack_kernel(
    const float* __restrict__ conv1_w, const float* __restrict__ conv1_b,
    const float* __restrict__ conv2_w, const float* __restrict__ conv2_b,
    const float* __restrict__ lin_w, const float* __restrict__ lin_b,
    const float* __restrict__ out_w,
    const float* __restrict__ bn1_g, const float* __restrict__ bn1_b,
    const float* __restrict__ bn1_m, const float* __restrict__ bn1_v,
    const float* __restrict__ bn2_g, const float* __restrict__ bn2_b,
    const float* __restrict__ bn2_m, const float* __restrict__ bn2_v,
    uint32_t* __restrict__ wlin4, uint32_t* __restrict__ cdat,
    uint32_t* __restrict__ lut, uint32_t* __restrict__ wout,
    int* __restrict__ Tlin)
{
    __shared__ uint32_t s_bm[122];
    __shared__ float    s_c1w[288];
    __shared__ uint32_t s_wp[32];
    __shared__ float    s_inv1[32], s_sh1[32], s_b1[32];

    int tid  = threadIdx.x;
    int lane = tid & 63;
    int wv   = tid >> 6;
    int b    = blockIdx.x;

    if (b < 500) {
        // ---- one lin_w row -> 128 packed k-words -> wlin4 scatter ----
        int j = b;
        if (tid == 0) { s_bm[120] = 0; s_bm[121] = 0; }
        for (int it = 0; it < 15; ++it) {
            int i = it * 256 + tid;                   // 0..3839
            float v = lin_w[(size_t)j * 3840 + i];
            uint64_t mask = __ballot(v > 0.0f);
            if (lane == 0)
                *((uint64_t*)&s_bm[(it * 256 + wv * 64) >> 5]) = mask;
        }
        __syncthreads();
        if (tid < 128) {
            int k = tid;
            int c = k >> 1, hi = k & 1;
            int nb = hi ? 28 : 32;
            int f0 = c * 60 + hi * 32;
            uint32_t lo  = s_bm[f0 >> 5];
            uint32_t hiw = s_bm[(f0 >> 5) + 1];
            int sh = f0 & 31;
            uint32_t word = (uint32_t)((((uint64_t)hiw << 32) | lo) >> sh);
            if (nb < 32) word &= (1u << nb) - 1u;
            int jw = j >> 6, jl = j & 63, kq = k >> 2, q = k & 3;
            wlin4[jw * 8192 + kq * 256 + jl * 4 + q] = word;
        }
        return;
    }

    int mb = b - 500;
    if (mb < 2) {
        // ---- conv1 LUT, LDS-staged ----
        for (int i = tid; i < 288; i += 256) s_c1w[i] = conv1_w[i];
        __syncthreads();
        if (tid < 32) {
            uint32_t wp = 0;
            for (int t = 0; t < 9; ++t)
                wp |= (s_c1w[tid * 9 + t] < 0.0f ? 1u : 0u) << t;
            s_wp[tid] = wp;
            float inv = bn1_g[tid] / sqrtf(bn1_v[tid] + BN_EPS);
            s_inv1[tid] = inv;
            s_sh1[tid]  = bn1_b[tid] - bn1_m[tid] * inv;
            s_b1[tid]   = conv1_b[tid];
        }
        __syncthreads();
        uint32_t px = (uint32_t)(mb * 256 + tid);     // 0..511
        uint32_t word = 0;
        for (int c = 0; c < 32; ++c) {
            int d = 9 - 2 * __popc(px ^ s_wp[c]);
            float z = __fadd_rn((float)d, s_b1[c]);
            z = __fadd_rn(__fmul_rn(z, s_inv1[c]), s_sh1[c]);
            word |= (z > 0.0f ? 1u : 0u) << c;
        }
        lut[px] = word;
        return;
    }

    int idx = (mb - 2) * 256 + tid;     // 0..1535
    if (idx < 576) {
        // conv2 masks, plane-major [tap][c] (complemented when inv < 0)
        int c = idx / 9, tap = idx % 9;
        uint32_t w = 0;
        for (int ic = 0; ic < 32; ++ic)
            w |= (conv2_w[c * 288 + ic * 9 + tap] > 0.0f ? 1u : 0u) << ic;
        float inv = bn2_g[c] / sqrtf(bn2_v[c] + BN_EPS);
        if (inv < 0.0f) w = ~w;
        cdat[tap * 64 + c] = w;
    } else if (idx < 576 + 64) {
        // conv2 integer thresholds
        int c = idx - 576;
        float inv = bn2_g[c] / sqrtf(bn2_v[c] + BN_EPS);
        float sh  = bn2_b[c] - bn2_m[c] * inv;
        float b2  = conv2_b[c];
        int T = 10000;
        for (int u = -300; u <= 300; ++u) {
            float v = (inv < 0.0f) ? (float)(-u) : (float)u;
            float z = __fadd_rn(__fmul_rn(__fadd_rn(v, b2), inv), sh);
            if (z > 0.0f) { T = u; break; }
        }
        cdat[576 + c] = (uint32_t)T;
    } else if (idx < 576 + 64 + 512) {
        // lin integer thresholds
        int j = idx - (576 + 64);
        int T = 10000;
        if (j < JLIN) {
            float lb = lin_b[j];
            int base = (int)floorf(-lb) - 2;
            for (int u = base; u <= base + 5; ++u)
                if (__fadd_rn((float)u, lb) > 0.0f) { T = u; break; }
        }
        Tlin[j] = T;
    } else if (idx < 576 + 64 + 512 + 160) {
        int t = idx - (576 + 64 + 512);
        int j = t >> 4, k = t & 15;
        uint32_t w = 0;
        for (int bb = 0; bb < 32; ++bb) {
            int jj = k * 32 + bb;
            if (jj < JLIN) w |= (out_w[j * 500 + jj] > 0.0f ? 1u : 0u) << bb;
        }
        wout[t] = w;
    }
}

// ---------------------------------------------------------------------------
// conv kernel: 4 samples/block (wave = sample), 2048 blocks.
//  ph1: flat ballot sign-pack (21 coalesced 256B loads/wave)
//  ph2: conv1 via LUT (funnel-extract 9-bit pattern from flat bitmap)
//  ph2.5: per-position window popcount sums (s_base)
//  ph3: lane = CHANNEL. masks+threshold in VGPRs (one coalesced load),
//       window words via wave-uniform LDS broadcasts (conflict-free),
//       bit p accumulated locally with static shifts (60 pos unrolled).
// ---------------------------------------------------------------------------
__global__ __launch_bounds__(256, 6) void conv_kernel(
    const float* __restrict__ x,
    const uint32_t* __restrict__ cdat,
    const uint32_t* __restrict__ lut,
    uint32_t* __restrict__ h2b, int* __restrict__ Bs)
{
    __shared__ __align__(8) uint32_t s_flat[4][44];
    __shared__ uint32_t s_lut[512];
    __shared__ __align__(8) uint32_t s_in[4][288];   // 286 used
    __shared__ uint32_t s_base[4][60];

    int tid  = threadIdx.x;
    int lane = tid & 63;
    int wv   = tid >> 6;
    int s    = blockIdx.x * 4 + wv;

    s_lut[tid]       = lut[tid];
    s_lut[tid + 256] = lut[tid + 256];

    // ph1: flat sign bitmap (1296 bits -> 21 ballots)
    const float* xs = x + (size_t)s * 1296;
    #pragma unroll
    for (int it = 0; it < 21; ++it) {
        int f = it * 64 + lane;
        float v = (f < 1296) ? xs[f] : 1.0f;
        uint64_t mk = __ballot(v < 0.0f);
        if (lane == 0) *((uint64_t*)&s_flat[wv][2 * it]) = mk;
    }
    __syncthreads();

    // ph2: conv1 via LUT
    for (int i = tid; i < 4 * 286; i += 256) {
        int sl = i / 286, p = i - sl * 286;
        int oy = p / 26, ox = p - oy * 26;
        uint32_t pxb = 0;
        #pragma unroll
        for (int ky = 0; ky < 3; ++ky) {
            int bitpos = 54 * (2 * oy + ky) + 2 * ox;
            int d  = bitpos >> 5;
            int sh = bitpos & 31;
            uint64_t wp = (uint64_t)s_flat[sl][d] | ((uint64_t)s_flat[sl][d + 1] << 32);
            pxb |= (((uint32_t)(wp >> sh)) & 7u) << (3 * ky);
        }
        s_in[sl][p] = s_lut[pxb];
    }
    __syncthreads();

    // ph2.5: window popcount base per output position
    for (int i = tid; i < 4 * 60; i += 256) {
        int sl = i / 60, p = i - sl * 60;
        int oy = p / 12, ox = p - 12 * oy;
        uint32_t sum = 0;
        #pragma unroll
        for (int ky = 0; ky < 3; ++ky) {
            const uint32_t* rp = &s_in[sl][(2 * oy + ky) * 26 + 2 * ox];
            sum += __popc(rp[0]) + __popc(rp[1]) + __popc(rp[2]);
        }
        s_base[sl][p] = sum;
    }
    __syncthreads();

    // ph3: lane = channel
    int c = lane;
    uint32_t m[9];
    #pragma unroll
    for (int q = 0; q < 9; ++q) m[q] = cdat[q * 64 + c];   // coalesced
    int T = (int)cdat[576 + c];

    uint32_t w0 = 0, w1 = 0;
    #pragma unroll
    for (int oy = 0; oy < 5; ++oy) {
        #pragma unroll
        for (int ox = 0; ox < 12; ++ox) {
            const int p = oy * 12 + ox;
            int P = 0;
            #pragma unroll
            for (int ky = 0; ky < 3; ++ky) {
                const uint32_t* rp = &s_in[wv][(2 * oy + ky) * 26 + 2 * ox];
                uint64_t ab = *(const uint64_t*)rp;       // uniform -> broadcast
                uint32_t t0 = (uint32_t)ab;
                uint32_t t1 = (uint32_t)(ab >> 32);
                uint32_t t2 = rp[2];
                P += __popc(t0 & m[ky * 3 + 0]);
                P += __popc(t1 & m[ky * 3 + 1]);
                P += __popc(t2 & m[ky * 3 + 2]);
            }
            int v = 2 * P - (int)s_base[wv][p];
            uint32_t bit = (v >= T) ? 1u : 0u;
            if (p < 32) w0 |= bit << p; else w1 |= bit << (p - 32);
        }
    }

    int bsum = __popc(w0) + __popc(w1);
    #pragma unroll
    for (int off = 32; off > 0; off >>= 1) bsum += __shfl_xor(bsum, off, 64);
    if (lane == 0) Bs[s] = bsum;

    *(uint2*)(h2b + (size_t)s * 128 + 2 * c) = make_uint2(w0, w1);
}

// ---------------------------------------------------------------------------
// lin+out fused: 512 blocks, one block = 16 samples, loops ALL 8 jw weight
// tiles through one 32 KB LDS buffer (XCD-proof reuse: wlin stays L2-hot,
// h2b read exactly once). After the jw loop the complete h3 for the block's
// samples sits in LDS -> out layer computed in-block, written to d_out.
// ---------------------------------------------------------------------------
__global__ __launch_bounds__(256) void lin_kernel(
    const uint32_t* __restrict__ h2b,
    const uint32_t* __restrict__ wlin4,
    const int* __restrict__ Tlin,
    const int* __restrict__ Bs,
    const uint32_t* __restrict__ wout,
    const float* __restrict__ out_b,
    float* __restrict__ out)
{
    __shared__ uint4    s_w[2048];       // 32 KB weight tile (one jw)
    __shared__ uint64_t s_h3[16][8];     // h3 bits per sample
    __shared__ uint64_t s_wout[10][8];

    int tid  = threadIdx.x;
    int lane = tid & 63;
    int wv   = __builtin_amdgcn_readfirstlane((int)(tid >> 6));
    int sbase = blockIdx.x * 16;

    if (tid < 80) ((uint64_t*)s_wout)[tid] = ((const uint64_t*)wout)[tid];

    for (int jw = 0; jw < 8; ++jw) {
        const uint4* wsrc = (const uint4*)wlin4 + (size_t)jw * 2048;
        #pragma unroll
        for (int i = 0; i < 8; ++i)
            s_w[i * 256 + tid] = wsrc[i * 256 + tid];
        int T = Tlin[jw * 64 + lane];
        __syncthreads();

        int smp = sbase + wv * 4;
        int P[4] = {0, 0, 0, 0};
        #pragma unroll 4
        for (int kq = 0; kq < 32; ++kq) {
            uint4 w4 = s_w[kq * 64 + lane];
            #pragma unroll
            for (int i = 0; i < 4; ++i) {
                uint4 a = *((const uint4*)(h2b + (size_t)(smp + i) * 128) + kq); // uniform -> s_load
                P[i] += __popc(a.x & w4.x);
                P[i] += __popc(a.y & w4.y);
                P[i] += __popc(a.z & w4.z);
                P[i] += __popc(a.w & w4.w);
            }
        }
        #pragma unroll
        for (int i = 0; i < 4; ++i) {
            int v = 2 * P[i] - Bs[smp + i];
            uint64_t mk = __ballot(v >= T);
            if (lane == 0) s_h3[wv * 4 + i][jw] = mk;
        }
        __syncthreads();
    }

    // out epilogue: 160 tasks = 16 samples x 10 outputs
    if (tid < 160) {
        int sl = tid / 10, o = tid - sl * 10;
        int P = 0, B = 0;
        #pragma unroll
        for (int k = 0; k < 8; ++k) {
            uint64_t a = s_h3[sl][k];
            P += __popcll(a & s_wout[o][k]);
            B += __popcll(a);
        }
        out[(size_t)(sbase + sl) * 10 + o] = __fadd_rn((float)(2 * P - B), out_b[o]);
    }
}

// ---------------------------------------------------------------------------
extern "C" void kernel_launch(void* const* d_in, const int* in_sizes, int n_in,
                              void* d_out, int out_size, void* d_ws, size_t ws_size,
                              hipStream_t stream)
{
    const float* x       = (const float*)d_in[0];
    const float* conv1_w = (const float*)d_in[1];
    const float* conv1_b = (const float*)d_in[2];
    const float* bn1_g   = (const float*)d_in[3];
    const float* bn1_b   = (const float*)d_in[4];
    const float* bn1_m   = (const float*)d_in[5];
    const float* bn1_v   = (const float*)d_in[6];
    const float* conv2_w = (const float*)d_in[7];
    const float* conv2_b = (const float*)d_in[8];
    const float* bn2_g   = (const float*)d_in[9];
    const float* bn2_b   = (const float*)d_in[10];
    const float* bn2_m   = (const float*)d_in[11];
    const float* bn2_v   = (const float*)d_in[12];
    const float* lin_w   = (const float*)d_in[13];
    const float* lin_b   = (const float*)d_in[14];
    const float* out_w   = (const float*)d_in[15];
    const float* out_b   = (const float*)d_in[16];

    char* ws = (char*)d_ws;
    uint32_t* h2b   = (uint32_t*)(ws + 0);
    uint32_t* wlin4 = (uint32_t*)(ws + 4718592);
    uint32_t* cdat  = (uint32_t*)(ws + 4980736);
    uint32_t* lut   = (uint32_t*)(ws + 4983296);
    uint32_t* wout  = (uint32_t*)(ws + 4985344);
    int*      Tlin  = (int*)     (ws + 4985984);
    int*      Bs    = (int*)     (ws + 4988032);

    pack_kernel<<<508, 256, 0, stream>>>(conv1_w, conv1_b, conv2_w, conv2_b,
                                         lin_w, lin_b, out_w,
                                         bn1_g, bn1_b, bn1_m, bn1_v,
                                         bn2_g, bn2_b, bn2_m, bn2_v,
                                         wlin4, cdat, lut, wout, Tlin);
    conv_kernel<<<NB / 4, 256, 0, stream>>>(x, cdat, lut, h2b, Bs);
    lin_kernel<<<512, 256, 0, stream>>>(h2b, wlin4, Tlin, Bs, wout, out_b,
                                        (float*)d_out);
}

// Round 8
// 199.555 us; speedup vs baseline: 1.3937x; 1.3937x over previous
//
#include <hip/hip_runtime.h>
#include <cstdint>

#define BN_EPS 1e-5f

static constexpr int NB = 8192;
static constexpr int JLIN = 500;

// ---------------------------------------------------------------------------
// ws layout
//  h2b   [8192][128] u32   @ 0         4 MB   (row-major per sample)
//  wlin4 [8][32][64][4] u32 @ 4718592  256 KB (per-jw LDS image: kq, j, q)
//  cdat  [640]       u32   @ 4980736   (masks plane-major [tap][c] + T[c] @576)
//  lut   [512]       u32   @ 4983296
//  wout  [10*16]     u32   @ 4985344   (read as u64[8] per o)
//  Tlin  [512]       i32   @ 4985984
//  Bs    [8192]      i32   @ 4988032   32 KB
// ---------------------------------------------------------------------------

// ---------------------------------------------------------------------------
// pack kernel, grid = 508 blocks (unchanged from R7)
// ---------------------------------------------------------------------------
__global__ __launch_bounds__(256) void pack_kernel(
    const float* __restrict__ conv1_w, const float* __restrict__ conv1_b,
    const float* __restrict__ conv2_w, const float* __restrict__ conv2_b,
    const float* __restrict__ lin_w, const float* __restrict__ lin_b,
    const float* __restrict__ out_w,
    const float* __restrict__ bn1_g, const float* __restrict__ bn1_b,
    const float* __restrict__ bn1_m, const float* __restrict__ bn1_v,
    const float* __restrict__ bn2_g, const float* __restrict__ bn2_b,
    const float* __restrict__ bn2_m, const float* __restrict__ bn2_v,
    uint32_t* __restrict__ wlin4, uint32_t* __restrict__ cdat,
    uint32_t* __restrict__ lut, uint32_t* __restrict__ wout,
    int* __restrict__ Tlin)
{
    __shared__ uint32_t s_bm[122];
    __shared__ float    s_c1w[288];
    __shared__ uint32_t s_wp[32];
    __shared__ float    s_inv1[32], s_sh1[32], s_b1[32];

    int tid  = threadIdx.x;
    int lane = tid & 63;
    int wv   = tid >> 6;
    int b    = blockIdx.x;

    if (b < 500) {
        // ---- one lin_w row -> 128 packed k-words -> wlin4 scatter ----
        int j = b;
        if (tid == 0) { s_bm[120] = 0; s_bm[121] = 0; }
        for (int it = 0; it < 15; ++it) {
            int i = it * 256 + tid;                   // 0..3839
            float v = lin_w[(size_t)j * 3840 + i];
            uint64_t mask = __ballot(v > 0.0f);
            if (lane == 0)
                *((uint64_t*)&s_bm[(it * 256 + wv * 64) >> 5]) = mask;
        }
        __syncthreads();
        if (tid < 128) {
            int k = tid;
            int c = k >> 1, hi = k & 1;
            int nb = hi ? 28 : 32;
            int f0 = c * 60 + hi * 32;
            uint32_t lo  = s_bm[f0 >> 5];
            uint32_t hiw = s_bm[(f0 >> 5) + 1];
            int sh = f0 & 31;
            uint32_t word = (uint32_t)((((uint64_t)hiw << 32) | lo) >> sh);
            if (nb < 32) word &= (1u << nb) - 1u;
            int jw = j >> 6, jl = j & 63, kq = k >> 2, q = k & 3;
            wlin4[jw * 8192 + kq * 256 + jl * 4 + q] = word;
        }
        return;
    }

    int mb = b - 500;
    if (mb < 2) {
        // ---- conv1 LUT, LDS-staged ----
        for (int i = tid; i < 288; i += 256) s_c1w[i] = conv1_w[i];
        __syncthreads();
        if (tid < 32) {
            uint32_t wp = 0;
            for (int t = 0; t < 9; ++t)
                wp |= (s_c1w[tid * 9 + t] < 0.0f ? 1u : 0u) << t;
            s_wp[tid] = wp;
            float inv = bn1_g[tid] / sqrtf(bn1_v[tid] + BN_EPS);
            s_inv1[tid] = inv;
            s_sh1[tid]  = bn1_b[tid] - bn1_m[tid] * inv;
            s_b1[tid]   = conv1_b[tid];
        }
        __syncthreads();
        uint32_t px = (uint32_t)(mb * 256 + tid);     // 0..511
        uint32_t word = 0;
        for (int c = 0; c < 32; ++c) {
            int d = 9 - 2 * __popc(px ^ s_wp[c]);
            float z = __fadd_rn((float)d, s_b1[c]);
            z = __fadd_rn(__fmul_rn(z, s_inv1[c]), s_sh1[c]);
            word |= (z > 0.0f ? 1u : 0u) << c;
        }
        lut[px] = word;
        return;
    }

    int idx = (mb - 2) * 256 + tid;     // 0..1535
    if (idx < 576) {
        // conv2 masks, plane-major [tap][c] (complemented when inv < 0)
        int c = idx / 9, tap = idx % 9;
        uint32_t w = 0;
        for (int ic = 0; ic < 32; ++ic)
            w |= (conv2_w[c * 288 + ic * 9 + tap] > 0.0f ? 1u : 0u) << ic;
        float inv = bn2_g[c] / sqrtf(bn2_v[c] + BN_EPS);
        if (inv < 0.0f) w = ~w;
        cdat[tap * 64 + c] = w;
    } else if (idx < 576 + 64) {
        // conv2 integer thresholds
        int c = idx - 576;
        float inv = bn2_g[c] / sqrtf(bn2_v[c] + BN_EPS);
        float sh  = bn2_b[c] - bn2_m[c] * inv;
        float b2  = conv2_b[c];
        int T = 10000;
        for (int u = -300; u <= 300; ++u) {
            float v = (inv < 0.0f) ? (float)(-u) : (float)u;
            float z = __fadd_rn(__fmul_rn(__fadd_rn(v, b2), inv), sh);
            if (z > 0.0f) { T = u; break; }
        }
        cdat[576 + c] = (uint32_t)T;
    } else if (idx < 576 + 64 + 512) {
        // lin integer thresholds
        int j = idx - (576 + 64);
        int T = 10000;
        if (j < JLIN) {
            float lb = lin_b[j];
            int base = (int)floorf(-lb) - 2;
            for (int u = base; u <= base + 5; ++u)
                if (__fadd_rn((float)u, lb) > 0.0f) { T = u; break; }
        }
        Tlin[j] = T;
    } else if (idx < 576 + 64 + 512 + 160) {
        int t = idx - (576 + 64 + 512);
        int j = t >> 4, k = t & 15;
        uint32_t w = 0;
        for (int bb = 0; bb < 32; ++bb) {
            int jj = k * 32 + bb;
            if (jj < JLIN) w |= (out_w[j * 500 + jj] > 0.0f ? 1u : 0u) << bb;
        }
        wout[t] = w;
    }
}

// ---------------------------------------------------------------------------
// conv kernel: 4 samples/block (wave = sample), 2048 blocks.
// NO min-waves bound: R7's (256,6) cap + unrolled ph3 spilled ~300 MB of
// scratch to HBM (WRITE_SIZE 240 MB, VALUBusy 20%). Pressure is instead
// bounded structurally: ph3 processes one 25-word row at a time.
// ---------------------------------------------------------------------------
__global__ __launch_bounds__(256) void conv_kernel(
    const float* __restrict__ x,
    const uint32_t* __restrict__ cdat,
    const uint32_t* __restrict__ lut,
    uint32_t* __restrict__ h2b, int* __restrict__ Bs)
{
    __shared__ __align__(8) uint32_t s_flat[4][44];
    __shared__ uint32_t s_lut[512];
    __shared__ __align__(8) uint32_t s_in[4][288];   // 286 used
    __shared__ uint32_t s_base[4][64];

    int tid  = threadIdx.x;
    int lane = tid & 63;
    int wv   = tid >> 6;
    int s    = blockIdx.x * 4 + wv;

    s_lut[tid]       = lut[tid];
    s_lut[tid + 256] = lut[tid + 256];

    // ph1: flat sign bitmap (1296 bits -> 21 ballots, coalesced)
    const float* xs = x + (size_t)s * 1296;
    #pragma unroll
    for (int it = 0; it < 21; ++it) {
        int f = it * 64 + lane;
        float v = (f < 1296) ? xs[f] : 1.0f;
        uint64_t mk = __ballot(v < 0.0f);
        if (lane == 0) *((uint64_t*)&s_flat[wv][2 * it]) = mk;
    }
    __syncthreads();

    // ph2: conv1 via LUT
    for (int i = tid; i < 4 * 286; i += 256) {
        int sl = i / 286, p = i - sl * 286;
        int oy = p / 26, ox = p - oy * 26;
        uint32_t pxb = 0;
        #pragma unroll
        for (int ky = 0; ky < 3; ++ky) {
            int bitpos = 54 * (2 * oy + ky) + 2 * ox;
            int d  = bitpos >> 5;
            int sh = bitpos & 31;
            uint64_t wp = (uint64_t)s_flat[sl][d] | ((uint64_t)s_flat[sl][d + 1] << 32);
            pxb |= (((uint32_t)(wp >> sh)) & 7u) << (3 * ky);
        }
        s_in[sl][p] = s_lut[pxb];
    }
    __syncthreads();

    // ph2.5: window popcount base per output position
    for (int i = tid; i < 4 * 60; i += 256) {
        int sl = i / 60, p = i - sl * 60;
        int oy = p / 12, ox = p - 12 * oy;
        uint32_t sum = 0;
        #pragma unroll
        for (int ky = 0; ky < 3; ++ky) {
            const uint32_t* rp = &s_in[sl][(2 * oy + ky) * 26 + 2 * ox];
            sum += __popc(rp[0]) + __popc(rp[1]) + __popc(rp[2]);
        }
        s_base[sl][p] = sum;
    }
    __syncthreads();

    // ph3: lane = channel; row-at-a-time to bound register pressure
    int c = lane;
    uint32_t m[9];
    #pragma unroll
    for (int q = 0; q < 9; ++q) m[q] = cdat[q * 64 + c];   // coalesced
    int T = (int)cdat[576 + c];

    uint64_t acc = 0;
    for (int oy = 0; oy < 5; ++oy) {
        int P[12];
        #pragma unroll
        for (int ox = 0; ox < 12; ++ox) P[ox] = 0;
        #pragma unroll
        for (int ky = 0; ky < 3; ++ky) {
            const uint32_t* rp = &s_in[wv][(2 * oy + ky) * 26];
            uint32_t r[25];
            #pragma unroll
            for (int d = 0; d < 12; ++d)
                *(uint64_t*)&r[2 * d] = *(const uint64_t*)&rp[2 * d];  // b64 broadcast
            r[24] = rp[24];
            uint32_t m0 = m[ky * 3 + 0], m1 = m[ky * 3 + 1], m2 = m[ky * 3 + 2];
            #pragma unroll
            for (int ox = 0; ox < 12; ++ox) {
                P[ox] += __popc(r[2 * ox]     & m0);
                P[ox] += __popc(r[2 * ox + 1] & m1);
                P[ox] += __popc(r[2 * ox + 2] & m2);
            }
        }
        const uint32_t* bp = &s_base[wv][oy * 12];
        uint32_t bits = 0;
        #pragma unroll
        for (int ox = 0; ox < 12; ++ox) {
            int v = 2 * P[ox] - (int)bp[ox];
            bits |= (v >= T ? 1u : 0u) << ox;
        }
        acc |= (uint64_t)bits << (12 * oy);
    }
    uint32_t w0 = (uint32_t)acc;
    uint32_t w1 = (uint32_t)(acc >> 32) & 0x0FFFFFFFu;

    int bsum = __popc(w0) + __popc(w1);
    #pragma unroll
    for (int off = 32; off > 0; off >>= 1) bsum += __shfl_xor(bsum, off, 64);
    if (lane == 0) Bs[s] = bsum;

    *(uint2*)(h2b + (size_t)s * 128 + 2 * c) = make_uint2(w0, w1);
}

// ---------------------------------------------------------------------------
// lin+out fused (unchanged from R7): 512 blocks, 16 samples/block, loops all
// 8 jw weight tiles through one 32 KB LDS buffer; out epilogue in-block.
// ---------------------------------------------------------------------------
__global__ __launch_bounds__(256) void lin_kernel(
    const uint32_t* __restrict__ h2b,
    const uint32_t* __restrict__ wlin4,
    const int* __restrict__ Tlin,
    const int* __restrict__ Bs,
    const uint32_t* __restrict__ wout,
    const float* __restrict__ out_b,
    float* __restrict__ out)
{
    __shared__ uint4    s_w[2048];       // 32 KB weight tile (one jw)
    __shared__ uint64_t s_h3[16][8];     // h3 bits per sample
    __shared__ uint64_t s_wout[10][8];

    int tid  = threadIdx.x;
    int lane = tid & 63;
    int wv   = __builtin_amdgcn_readfirstlane((int)(tid >> 6));
    int sbase = blockIdx.x * 16;

    if (tid < 80) ((uint64_t*)s_wout)[tid] = ((const uint64_t*)wout)[tid];

    for (int jw = 0; jw < 8; ++jw) {
        const uint4* wsrc = (const uint4*)wlin4 + (size_t)jw * 2048;
        #pragma unroll
        for (int i = 0; i < 8; ++i)
            s_w[i * 256 + tid] = wsrc[i * 256 + tid];
        int T = Tlin[jw * 64 + lane];
        __syncthreads();

        int smp = sbase + wv * 4;
        int P[4] = {0, 0, 0, 0};
        #pragma unroll 4
        for (int kq = 0; kq < 32; ++kq) {
            uint4 w4 = s_w[kq * 64 + lane];
            #pragma unroll
            for (int i = 0; i < 4; ++i) {
                uint4 a = *((const uint4*)(h2b + (size_t)(smp + i) * 128) + kq); // uniform -> s_load
                P[i] += __popc(a.x & w4.x);
                P[i] += __popc(a.y & w4.y);
                P[i] += __popc(a.z & w4.z);
                P[i] += __popc(a.w & w4.w);
            }
        }
        #pragma unroll
        for (int i = 0; i < 4; ++i) {
            int v = 2 * P[i] - Bs[smp + i];
            uint64_t mk = __ballot(v >= T);
            if (lane == 0) s_h3[wv * 4 + i][jw] = mk;
        }
        __syncthreads();
    }

    // out epilogue: 160 tasks = 16 samples x 10 outputs
    if (tid < 160) {
        int sl = tid / 10, o = tid - sl * 10;
        int P = 0, B = 0;
        #pragma unroll
        for (int k = 0; k < 8; ++k) {
            uint64_t a = s_h3[sl][k];
            P += __popcll(a & s_wout[o][k]);
            B += __popcll(a);
        }
        out[(size_t)(sbase + sl) * 10 + o] = __fadd_rn((float)(2 * P - B), out_b[o]);
    }
}

// ---------------------------------------------------------------------------
extern "C" void kernel_launch(void* const* d_in, const int* in_sizes, int n_in,
                              void* d_out, int out_size, void* d_ws, size_t ws_size,
                              hipStream_t stream)
{
    const float* x       = (const float*)d_in[0];
    const float* conv1_w = (const float*)d_in[1];
    const float* conv1_b = (const float*)d_in[2];
    const float* bn1_g   = (const float*)d_in[3];
    const float* bn1_b   = (const float*)d_in[4];
    const float* bn1_m   = (const float*)d_in[5];
    const float* bn1_v   = (const float*)d_in[6];
    const float* conv2_w = (const float*)d_in[7];
    const float* conv2_b = (const float*)d_in[8];
    const float* bn2_g   = (const float*)d_in[9];
    const float* bn2_b   = (const float*)d_in[10];
    const float* bn2_m   = (const float*)d_in[11];
    const float* bn2_v   = (const float*)d_in[12];
    const float* lin_w   = (const float*)d_in[13];
    const float* lin_b   = (const float*)d_in[14];
    const float* out_w   = (const float*)d_in[15];
    const float* out_b   = (const float*)d_in[16];

    char* ws = (char*)d_ws;
    uint32_t* h2b   = (uint32_t*)(ws + 0);
    uint32_t* wlin4 = (uint32_t*)(ws + 4718592);
    uint32_t* cdat  = (uint32_t*)(ws + 4980736);
    uint32_t* lut   = (uint32_t*)(ws + 4983296);
    uint32_t* wout  = (uint32_t*)(ws + 4985344);
    int*      Tlin  = (int*)     (ws + 4985984);
    int*      Bs    = (int*)     (ws + 4988032);

    pack_kernel<<<508, 256, 0, stream>>>(conv1_w, conv1_b, conv2_w, conv2_b,
                                         lin_w, lin_b, out_w,
                                         bn1_g, bn1_b, bn1_m, bn1_v,
                                         bn2_g, bn2_b, bn2_m, bn2_v,
                                         wlin4, cdat, lut, wout, Tlin);
    conv_kernel<<<NB / 4, 256, 0, stream>>>(x, cdat, lut, h2b, Bs);
    lin_kernel<<<512, 256, 0, stream>>>(h2b, wlin4, Tlin, Bs, wout, out_b,
                                        (float*)d_out);
}